// Round 3
// baseline (2903.927 us; speedup 1.0000x reference)
//
#include <hip/hip_runtime.h>
#include <math.h>

typedef _Float16 half2v __attribute__((ext_vector_type(2)));

#define TT 2048
#define CH 20   // padded dword stride per 16-dword h-chunk (bank spread: c*20%32)

#if __has_builtin(__builtin_amdgcn_fdot2)
#define FDOT2(a,b,c) __builtin_amdgcn_fdot2((a),(b),(c),false)
#else
#define FDOT2(a,b,c) ((c) + (float)(a).x*(float)(b).x + (float)(a).y*(float)(b).y)
#endif

__global__ __launch_bounds__(1024, 4)
void janet_rnn(const float* __restrict__ x,
               const float* __restrict__ w_ih,
               const float* __restrict__ w_hh,
               const float* __restrict__ b_ih,
               const float* __restrict__ b_hh,
               const float* __restrict__ fc_w,
               const float* __restrict__ fc_b,
               float* __restrict__ out)
{
    __shared__ unsigned int hbuf[2][8 * CH];   // ping-pong packed-f16 h
    __shared__ float dm[512];
    __shared__ float fcw[512];                 // [o][256]

    const int tid = threadIdx.x;
    const int b   = blockIdx.x;
    const int cc  = tid & 7;        // column chunk 0..7 (32 h-cols each)
    const int rg  = tid >> 3;       // row group 0..127 (4 rows each)
    const int r0  = rg * 4;
    const int c0  = cc * 32;

    // ---------------- init ----------------
    if (tid < 8 * CH) { hbuf[0][tid] = 0u; hbuf[1][tid] = 0u; }
    if (tid < 512) fcw[tid] = fc_w[tid];

    // W_hh fragment: rows r0..r0+3 x cols c0..c0+31, packed f16, register-resident
    half2v wp[4][16];
    #pragma unroll
    for (int i = 0; i < 4; ++i) {
        const float* wr = w_hh + (r0 + i) * 256 + c0;
        #pragma unroll
        for (int j = 0; j < 8; ++j) {
            const float4 v = *reinterpret_cast<const float4*>(wr + j * 4);
            half2v p0; p0.x = (_Float16)v.x; p0.y = (_Float16)v.y;
            half2v p1; p1.x = (_Float16)v.z; p1.y = (_Float16)v.w;
            wp[i][j * 2 + 0] = p0;
            wp[i][j * 2 + 1] = p1;
        }
    }

    // phase-3 per-thread constants in registers (tid < 256)
    float wf[6], wg[6], bsf = 0.f, bsg = 0.f;
    if (tid < 256) {
        #pragma unroll
        for (int c = 0; c < 6; ++c) {
            wf[c] = w_ih[tid * 6 + c];
            wg[c] = w_ih[(256 + tid) * 6 + c];
        }
        bsf = b_ih[tid]       + b_hh[tid];
        bsg = b_ih[256 + tid] + b_hh[256 + tid];
    }
    const int pl = tid - 256;                  // projection wave: tids 256..319
    const float fcb0 = fc_b[0], fcb1 = fc_b[1];

    float hreg = 0.0f;                         // own h element (tid<256), h_0 = 0

    const float* xb   = x   + (size_t)b * TT * 2;
    float*       outb = out + (size_t)b * TT * 2;

    __syncthreads();

    #pragma unroll 1
    for (int t = 0; t < TT; ++t) {
        // prefetch x[t]; consumed only after barrier A
        float xi = 0.f, xq = 0.f;
        if (tid < 256) {
            const float2 xv = *reinterpret_cast<const float2*>(xb + 2 * t);
            xi = xv.x; xq = xv.y;
        }

        // ---- matvec: dm = W_hh @ h_{t-1}  (h in hbuf[(t+1)&1]) ----
        const unsigned int* hb = &hbuf[(t + 1) & 1][cc * CH];
        float a0 = 0.f, a1 = 0.f, a2 = 0.f, a3 = 0.f;
        #pragma unroll
        for (int q = 0; q < 4; ++q) {
            const uint4 r = *reinterpret_cast<const uint4*>(hb + 4 * q);
            const half2v h0 = __builtin_bit_cast(half2v, r.x);
            const half2v h1 = __builtin_bit_cast(half2v, r.y);
            const half2v h2 = __builtin_bit_cast(half2v, r.z);
            const half2v h3 = __builtin_bit_cast(half2v, r.w);
            a0 = FDOT2(wp[0][q*4+0], h0, a0); a0 = FDOT2(wp[0][q*4+1], h1, a0);
            a0 = FDOT2(wp[0][q*4+2], h2, a0); a0 = FDOT2(wp[0][q*4+3], h3, a0);
            a1 = FDOT2(wp[1][q*4+0], h0, a1); a1 = FDOT2(wp[1][q*4+1], h1, a1);
            a1 = FDOT2(wp[1][q*4+2], h2, a1); a1 = FDOT2(wp[1][q*4+3], h3, a1);
            a2 = FDOT2(wp[2][q*4+0], h0, a2); a2 = FDOT2(wp[2][q*4+1], h1, a2);
            a2 = FDOT2(wp[2][q*4+2], h2, a2); a2 = FDOT2(wp[2][q*4+3], h3, a2);
            a3 = FDOT2(wp[3][q*4+0], h0, a3); a3 = FDOT2(wp[3][q*4+1], h1, a3);
            a3 = FDOT2(wp[3][q*4+2], h2, a3); a3 = FDOT2(wp[3][q*4+3], h3, a3);
        }
        // reduce the 8 column-chunks (lanes cc = tid&7: xor 1,2,4)
        a0 += __shfl_xor(a0, 1); a0 += __shfl_xor(a0, 2); a0 += __shfl_xor(a0, 4);
        a1 += __shfl_xor(a1, 1); a1 += __shfl_xor(a1, 2); a1 += __shfl_xor(a1, 4);
        a2 += __shfl_xor(a2, 1); a2 += __shfl_xor(a2, 2); a2 += __shfl_xor(a2, 4);
        a3 += __shfl_xor(a3, 1); a3 += __shfl_xor(a3, 2); a3 += __shfl_xor(a3, 4);
        if (cc == 0)
            *reinterpret_cast<float4*>(&dm[r0]) = make_float4(a0, a1, a2, a3);
        __syncthreads();   // barrier A: dm ready

        if (tid < 256) {
            // ---- gates + h update, 1 element/thread ----
            const float amp  = sqrtf(xi * xi + xq * xq);
            const float amp3 = amp * amp * amp;
            const float snv  = xq / amp;
            const float csv  = xi / amp;
            float dmf = dm[tid]       + bsf;
            float dmg = dm[256 + tid] + bsg;
            dmf += wf[0]*xi + wf[1]*xq + wf[2]*amp + wf[3]*amp3 + wf[4]*snv + wf[5]*csv;
            dmg += wg[0]*xi + wg[1]*xq + wg[2]*amp + wg[3]*amp3 + wg[4]*snv + wg[5]*csv;
            const float gf = 1.0f / (1.0f + __expf(-dmf));
            const float gg = 1.0f / (1.0f + __expf(-dmg));
            hreg = (1.0f - gf) * gg + gf * hreg;
            // pack pair (even lane packs self + odd neighbor)
            const float hhi = __shfl_down(hreg, 1);
            if ((tid & 1) == 0) {
                half2v hp2; hp2.x = (_Float16)hreg; hp2.y = (_Float16)hhi;
                const int d = tid >> 1;                 // dword index 0..127
                hbuf[t & 1][(d >> 4) * CH + (d & 15)] =
                    __builtin_bit_cast(unsigned int, hp2);
            }
        } else if (pl < 64 && t > 0) {
            // ---- projection wave: out[t-1] = fc_w @ h_{t-1} + fc_b ----
            const unsigned int* hp = hbuf[(t + 1) & 1];
            const int d0 = 2 * pl, d1 = 2 * pl + 1;
            const half2v ha = __builtin_bit_cast(half2v, hp[(d0 >> 4) * CH + (d0 & 15)]);
            const half2v hc = __builtin_bit_cast(half2v, hp[(d1 >> 4) * CH + (d1 & 15)]);
            const float h0v = (float)ha.x, h1v = (float)ha.y;
            const float h2v = (float)hc.x, h3v = (float)hc.y;
            const float4 w0 = *reinterpret_cast<const float4*>(&fcw[4 * pl]);
            const float4 w1 = *reinterpret_cast<const float4*>(&fcw[256 + 4 * pl]);
            float po0 = w0.x*h0v + w0.y*h1v + w0.z*h2v + w0.w*h3v;
            float po1 = w1.x*h0v + w1.y*h1v + w1.z*h2v + w1.w*h3v;
            #pragma unroll
            for (int s = 1; s < 64; s <<= 1) {
                po0 += __shfl_xor(po0, s);
                po1 += __shfl_xor(po1, s);
            }
            if (pl == 0)
                *reinterpret_cast<float2*>(outb + (t - 1) * 2) =
                    make_float2(po0 + fcb0, po1 + fcb1);
        }
        __syncthreads();   // barrier B: h_t packed & visible
    }

    // final projection: h_{TT-1} is in hbuf[(TT-1)&1]
    if (pl >= 0 && pl < 64) {
        const unsigned int* hp = hbuf[(TT - 1) & 1];
        const int d0 = 2 * pl, d1 = 2 * pl + 1;
        const half2v ha = __builtin_bit_cast(half2v, hp[(d0 >> 4) * CH + (d0 & 15)]);
        const half2v hc = __builtin_bit_cast(half2v, hp[(d1 >> 4) * CH + (d1 & 15)]);
        const float h0v = (float)ha.x, h1v = (float)ha.y;
        const float h2v = (float)hc.x, h3v = (float)hc.y;
        const float4 w0 = *reinterpret_cast<const float4*>(&fcw[4 * pl]);
        const float4 w1 = *reinterpret_cast<const float4*>(&fcw[256 + 4 * pl]);
        float po0 = w0.x*h0v + w0.y*h1v + w0.z*h2v + w0.w*h3v;
        float po1 = w1.x*h0v + w1.y*h1v + w1.z*h2v + w1.w*h3v;
        #pragma unroll
        for (int s = 1; s < 64; s <<= 1) {
            po0 += __shfl_xor(po0, s);
            po1 += __shfl_xor(po1, s);
        }
        if (pl == 0)
            *reinterpret_cast<float2*>(outb + (TT - 1) * 2) =
                make_float2(po0 + fcb0, po1 + fcb1);
    }
}

extern "C" void kernel_launch(void* const* d_in, const int* in_sizes, int n_in,
                              void* d_out, int out_size, void* d_ws, size_t ws_size,
                              hipStream_t stream) {
    (void)in_sizes; (void)n_in; (void)out_size; (void)d_ws; (void)ws_size;
    const float* x    = (const float*)d_in[0];
    // d_in[1] = h_0 : reference ignores it (uses zeros)
    const float* w_ih = (const float*)d_in[2];
    const float* w_hh = (const float*)d_in[3];
    const float* b_ih = (const float*)d_in[4];
    const float* b_hh = (const float*)d_in[5];
    const float* fc_w = (const float*)d_in[6];
    const float* fc_b = (const float*)d_in[7];
    float* outp = (float*)d_out;

    hipLaunchKernelGGL(janet_rnn, dim3(64), dim3(1024), 0, stream,
                       x, w_ih, w_hh, b_ih, b_hh, fc_w, fc_b, outp);
}